// Round 1
// baseline (165.671 us; speedup 1.0000x reference)
//
#include <hip/hip_runtime.h>
#include <hip/hip_bf16.h>

// Problem constants (B=8192, D=512 from reference setup_inputs)
#define BN_ 8192
#define DK_ 512
#define TEMP_INV 14.2857142857142857f   // 1/0.07
#define LOG2E_ 1.44269504088896f
#define MAXOFF 15.0f                    // fixed lse offset; sim in [-14.3, 14.3]

typedef __bf16 bf16x8 __attribute__((ext_vector_type(8)));
typedef float f32x4 __attribute__((ext_vector_type(4)));

__device__ inline unsigned short f2bf(float f) {
    unsigned u = __float_as_uint(f);
    return (unsigned short)((u + 0x7FFFu + ((u >> 16) & 1u)) >> 16);
}

// ---------------- Kernel 1: L2-normalize rows, write bf16 ----------------
__global__ __launch_bounds__(256) void norm_kernel(const float* __restrict__ emb,
                                                   unsigned short* __restrict__ ebf) {
    const int row  = blockIdx.x * 4 + (threadIdx.x >> 6);
    const int lane = threadIdx.x & 63;
    const float4* src = reinterpret_cast<const float4*>(emb + (size_t)row * DK_);
    float4 v0 = src[lane];        // cols lane*4 .. +3
    float4 v1 = src[lane + 64];   // cols 256 + lane*4 .. +3
    float ss = v0.x*v0.x + v0.y*v0.y + v0.z*v0.z + v0.w*v0.w
             + v1.x*v1.x + v1.y*v1.y + v1.z*v1.z + v1.w*v1.w;
#pragma unroll
    for (int off = 1; off < 64; off <<= 1) ss += __shfl_xor(ss, off, 64);
    const float scale = 1.0f / fmaxf(sqrtf(ss), 1e-12f);
    uint2 o0, o1;
    o0.x = (unsigned)f2bf(v0.x * scale) | ((unsigned)f2bf(v0.y * scale) << 16);
    o0.y = (unsigned)f2bf(v0.z * scale) | ((unsigned)f2bf(v0.w * scale) << 16);
    o1.x = (unsigned)f2bf(v1.x * scale) | ((unsigned)f2bf(v1.y * scale) << 16);
    o1.y = (unsigned)f2bf(v1.z * scale) | ((unsigned)f2bf(v1.w * scale) << 16);
    uint2* dst = reinterpret_cast<uint2*>(ebf + (size_t)row * DK_);
    dst[lane]      = o0;
    dst[lane + 64] = o1;
}

// ---------------- Kernel 2: fused 128x128 MFMA tile + row reductions ----------------
// grid (64, 64); 256 threads = 4 waves, each wave owns a 64x64 quadrant (4x4 frags 16x16x32)
__global__ __launch_bounds__(256, 2) void infonce_main(
    const unsigned short* __restrict__ ebf,
    const int* __restrict__ mask,
    float* __restrict__ se, float* __restrict__ ps, float* __restrict__ ct) {

    __shared__ unsigned short As[128 * 64];
    __shared__ unsigned short Bs[128 * 64];

    const int t    = threadIdx.x;
    const int lane = t & 63;
    const int wid  = t >> 6;
    const int wr   = wid >> 1;   // wave row 0..1
    const int wc   = wid & 1;    // wave col 0..1
    const int rb   = blockIdx.x; // row block
    const int cb   = blockIdx.y; // col block

    f32x4 acc[4][4] = {};

    // staging map: thread t -> row t/8 (of 32), 16B chunk (t%8) within 64-elem k-row
    const int sr = t >> 3;
    const int sc = (t & 7) * 8;
    const size_t arow0 = (size_t)(rb * 128 + sr) * DK_ + sc;
    const size_t brow0 = (size_t)(cb * 128 + sr) * DK_ + sc;

    for (int kt = 0; kt < 8; ++kt) {
        const int k0 = kt * 64;
#pragma unroll
        for (int s = 0; s < 4; ++s) {
            __builtin_amdgcn_global_load_lds(
                (const __attribute__((address_space(1))) void*)(ebf + arow0 + (size_t)s * 32 * DK_ + k0),
                (__attribute__((address_space(3))) void*)(As + s * 2048 + t * 8),
                16, 0, 0);
        }
#pragma unroll
        for (int s = 0; s < 4; ++s) {
            __builtin_amdgcn_global_load_lds(
                (const __attribute__((address_space(1))) void*)(ebf + brow0 + (size_t)s * 32 * DK_ + k0),
                (__attribute__((address_space(3))) void*)(Bs + s * 2048 + t * 8),
                16, 0, 0);
        }
        __syncthreads();   // compiler emits vmcnt(0) drain before barrier

        const int r16 = lane & 15;
        const int kg  = (lane >> 4) * 8;
#pragma unroll
        for (int ks = 0; ks < 2; ++ks) {
            bf16x8 af[4], bfr[4];
#pragma unroll
            for (int fm = 0; fm < 4; ++fm)
                af[fm] = *reinterpret_cast<const bf16x8*>(As + (wr * 64 + fm * 16 + r16) * 64 + ks * 32 + kg);
#pragma unroll
            for (int fn = 0; fn < 4; ++fn)
                bfr[fn] = *reinterpret_cast<const bf16x8*>(Bs + (wc * 64 + fn * 16 + r16) * 64 + ks * 32 + kg);
#pragma unroll
            for (int fm = 0; fm < 4; ++fm)
#pragma unroll
                for (int fn = 0; fn < 4; ++fn)
                    acc[fm][fn] = __builtin_amdgcn_mfma_f32_16x16x32_bf16(af[fm], bfr[fn], acc[fm][fn], 0, 0, 0);
        }
        __syncthreads();
    }

    // ---- epilogue: per-row partial {sum exp(sim-15), pos_sum, count} ----
    // C/D layout: col = lane&15, row = (lane>>4)*4 + reg
    const int colBase = cb * 128 + wc * 64 + (lane & 15);
    const int rowBase = rb * 128 + wr * 64 + ((lane >> 4) << 2);
    const float C1 = TEMP_INV * LOG2E_;
    const float C2 = -MAXOFF * LOG2E_;
#pragma unroll
    for (int fm = 0; fm < 4; ++fm) {
#pragma unroll
        for (int q = 0; q < 4; ++q) {
            const int i = rowBase + fm * 16 + q;
            const int* mrow = mask + (size_t)i * BN_;
            float lsep = 0.f, posp = 0.f, cntp = 0.f;
#pragma unroll
            for (int fn = 0; fn < 4; ++fn) {
                const int j = colBase + fn * 16;
                const float a = acc[fm][fn][q];   // raw dot (unit vectors), *1/T later
                const int m = mrow[j];
                const bool diag = (i == j);
                const float ex = diag ? 0.0f : exp2f(fmaf(a, C1, C2));
                lsep += ex;
                const bool p = (m != 0) && (!diag);
                posp += p ? a * TEMP_INV : 0.0f;
                cntp += p ? 1.0f : 0.0f;
            }
            // reduce across the 16 lanes sharing this row (lane&15 = 0..15)
#pragma unroll
            for (int off = 1; off < 16; off <<= 1) {
                lsep += __shfl_xor(lsep, off, 64);
                posp += __shfl_xor(posp, off, 64);
                cntp += __shfl_xor(cntp, off, 64);
            }
            if ((lane & 15) == 0) {
                atomicAdd(&se[i], lsep);
                atomicAdd(&ps[i], posp);
                atomicAdd(&ct[i], cntp);
            }
        }
    }
}

// ---------------- Kernel 3: finalize scalar loss ----------------
__global__ __launch_bounds__(256) void finalize_kernel(const float* __restrict__ se,
                                                       const float* __restrict__ ps,
                                                       const float* __restrict__ ct,
                                                       float* __restrict__ out) {
    __shared__ float red[256];
    const int t = threadIdx.x;
    float a = 0.f;
    for (int i = t; i < BN_; i += 256) {
        const float lse = logf(se[i]) + MAXOFF;
        a += lse - ps[i] / fmaxf(ct[i], 1.0f);
    }
    red[t] = a;
    __syncthreads();
    for (int s = 128; s > 0; s >>= 1) {
        if (t < s) red[t] += red[t + s];
        __syncthreads();
    }
    if (t == 0) out[0] = red[0] / (float)BN_;
}

extern "C" void kernel_launch(void* const* d_in, const int* in_sizes, int n_in,
                              void* d_out, int out_size, void* d_ws, size_t ws_size,
                              hipStream_t stream) {
    const float* emb  = (const float*)d_in[0];
    const int*   mask = (const int*)d_in[1];
    float* out = (float*)d_out;

    char* ws = (char*)d_ws;
    unsigned short* ebf = (unsigned short*)ws;                  // 8192*512*2 = 8 MB
    float* se = (float*)(ws + (size_t)BN_ * DK_ * 2);           // sum exp(sim-15)
    float* ps = se + BN_;                                       // positive sum
    float* ct = ps + BN_;                                       // positive count

    hipMemsetAsync(se, 0, (size_t)3 * BN_ * sizeof(float), stream);
    norm_kernel<<<BN_ / 4, 256, 0, stream>>>(emb, ebf);
    infonce_main<<<dim3(64, 64), 256, 0, stream>>>(ebf, mask, se, ps, ct);
    finalize_kernel<<<1, 256, 0, stream>>>(se, ps, ct, out);
}